// Round 1
// baseline (130.204 us; speedup 1.0000x reference)
//
#include <hip/hip_runtime.h>
#include <cmath>

// Radon backprojection: out[b, y, x] = sum_a lerp(sino[b, a, :], f(a,x,y))
//   f = (cx*cos(theta_a) + cy*sin(theta_a) - positions[0]) / dp
//   cx = x - (N-1)/2,  cy = -(y - (N-1)/2)
//
// One thread per pixel; BATCH accumulators per thread (index math shared
// across batches). cos/sin staged into LDS once per block.

template <int BATCH>
__global__ __launch_bounds__(256) void radon_bwd_kernel(
    const float* __restrict__ sino,
    const float* __restrict__ thetas,
    const float* __restrict__ positions,
    float* __restrict__ out,
    int A, int P, int N)
{
    __shared__ float s_cs[256];
    __shared__ float s_sn[256];
    const int tid = threadIdx.x;
    if (tid < A) {
        float th = thetas[tid];
        s_cs[tid] = cosf(th);
        s_sn[tid] = sinf(th);
    }
    __syncthreads();

    const int nn  = N * N;
    const int pix = blockIdx.x * blockDim.x + tid;
    if (pix >= nn) return;

    const int x = pix % N;
    const int y = pix / N;
    const float half = (float)(N - 1) * 0.5f;
    const float cx = (float)x - half;
    const float cy = half - (float)y;          // = -(y - half)

    const float p0     = positions[0];
    const float inv_dp = 1.0f / (positions[1] - p0);

    const int bstride = A * P;                 // elements per batch
    const float* sb = sino + (size_t)blockIdx.y * (size_t)BATCH * bstride;

    float acc[BATCH];
#pragma unroll
    for (int b = 0; b < BATCH; ++b) acc[b] = 0.0f;

    for (int a = 0; a < A; ++a) {
        // f = (cx*cos + cy*sin - p0) * inv_dp
        float f   = fmaf(cx, s_cs[a], fmaf(cy, s_sn[a], -p0)) * inv_dp;
        float i0f = floorf(f);
        int   i0  = (int)i0f;
        float w   = f - i0f;
        if (i0 >= 0 && i0 <= P - 2) {
            const float* row = sb + a * P + i0;
#pragma unroll
            for (int b = 0; b < BATCH; ++b) {
                float v0 = row[(size_t)b * bstride];
                float v1 = row[(size_t)b * bstride + 1];
                // v0*(1-w) + v1*w == v0 + w*(v1-v0)
                acc[b] = fmaf(w, v1 - v0, acc[b] + v0);
            }
        }
    }

    float* ob = out + (size_t)blockIdx.y * (size_t)BATCH * nn + pix;
#pragma unroll
    for (int b = 0; b < BATCH; ++b) ob[(size_t)b * nn] = acc[b];
}

extern "C" void kernel_launch(void* const* d_in, const int* in_sizes, int n_in,
                              void* d_out, int out_size, void* d_ws, size_t ws_size,
                              hipStream_t stream) {
    const float* sino      = (const float*)d_in[0];
    const float* thetas    = (const float*)d_in[1];
    const float* positions = (const float*)d_in[2];
    float* out             = (float*)d_out;

    const int A  = in_sizes[1];               // 180
    const int P  = in_sizes[2];               // 384
    const int BC = in_sizes[0] / (A * P);     // B*C = 4
    // out_size = BC * N * N
    const int N  = (int)lroundf(sqrtf((float)(out_size / BC)));
    const int nn = N * N;

    dim3 block(256);
    if (BC == 4 && A <= 256) {
        dim3 grid((nn + 255) / 256, 1);
        radon_bwd_kernel<4><<<grid, block, 0, stream>>>(
            sino, thetas, positions, out, A, P, N);
    } else {
        dim3 grid((nn + 255) / 256, (unsigned)BC);
        radon_bwd_kernel<1><<<grid, block, 0, stream>>>(
            sino, thetas, positions, out, A, P, N);
    }
}

// Round 2
// 86.866 us; speedup vs baseline: 1.4989x; 1.4989x over previous
//
#include <hip/hip_runtime.h>
#include <cmath>

// Radon backprojection, angle-chunked for occupancy.
//   out[b, y, x] = sum_a lerp(sino[b, a, :], f(a,x,y))
//   f = (cx*cos(theta_a) + cy*sin(theta_a) - p0) / dp
//
// R1 showed 11% occupancy (256 blocks -> 1 wave/SIMD), latency-bound.
// R2: grid = (nn/256) x ACHUNKS; each block accumulates a partial sum over
// ~A/ACHUNKS angles and atomicAdd-commits. d_out zeroed via hipMemsetAsync.

template <int BATCH>
__global__ __launch_bounds__(256) void radon_bwd_kernel(
    const float* __restrict__ sino,
    const float* __restrict__ thetas,
    const float* __restrict__ positions,
    float* __restrict__ out,
    int A, int P, int N, int chunk)
{
    __shared__ float s_cs[256];
    __shared__ float s_sn[256];
    const int tid = threadIdx.x;
    if (tid < A) {
        float th = thetas[tid];
        s_cs[tid] = cosf(th);
        s_sn[tid] = sinf(th);
    }
    __syncthreads();

    const int nn  = N * N;
    const int pix = blockIdx.x * blockDim.x + tid;
    if (pix >= nn) return;

    const int a0 = blockIdx.y * chunk;
    const int a1 = min(A, a0 + chunk);

    const int x = pix % N;
    const int y = pix / N;
    const float half = (float)(N - 1) * 0.5f;
    const float cx = (float)x - half;
    const float cy = half - (float)y;          // = -(y - half)

    const float p0     = positions[0];
    const float inv_dp = 1.0f / (positions[1] - p0);

    const int bstride = A * P;                 // elements per batch

    float acc[BATCH];
#pragma unroll
    for (int b = 0; b < BATCH; ++b) acc[b] = 0.0f;

    for (int a = a0; a < a1; ++a) {
        float f   = fmaf(cx, s_cs[a], fmaf(cy, s_sn[a], -p0)) * inv_dp;
        float i0f = floorf(f);
        int   i0  = (int)i0f;
        float w   = f - i0f;
        if (i0 >= 0 && i0 <= P - 2) {
            const float* row = sino + a * P + i0;
#pragma unroll
            for (int b = 0; b < BATCH; ++b) {
                float v0 = row[(size_t)b * bstride];
                float v1 = row[(size_t)b * bstride + 1];
                acc[b] = fmaf(w, v1 - v0, acc[b] + v0);   // v0 + w*(v1-v0)
            }
        }
    }

    float* ob = out + pix;
#pragma unroll
    for (int b = 0; b < BATCH; ++b)
        atomicAdd(ob + (size_t)b * nn, acc[b]);
}

extern "C" void kernel_launch(void* const* d_in, const int* in_sizes, int n_in,
                              void* d_out, int out_size, void* d_ws, size_t ws_size,
                              hipStream_t stream) {
    const float* sino      = (const float*)d_in[0];
    const float* thetas    = (const float*)d_in[1];
    const float* positions = (const float*)d_in[2];
    float* out             = (float*)d_out;

    const int A  = in_sizes[1];               // 180
    const int P  = in_sizes[2];               // 384
    const int BC = in_sizes[0] / (A * P);     // B*C = 4
    const int N  = (int)lroundf(sqrtf((float)(out_size / BC)));
    const int nn = N * N;

    // Harness poisons d_out with 0xAA; we accumulate atomically, so zero it.
    hipMemsetAsync(d_out, 0, (size_t)out_size * sizeof(float), stream);

    const int ACHUNKS = 8;                    // 2048 blocks -> 32 waves/CU
    const int chunk   = (A + ACHUNKS - 1) / ACHUNKS;

    dim3 block(256);
    if (BC == 4 && A <= 256) {
        dim3 grid((nn + 255) / 256, ACHUNKS);
        radon_bwd_kernel<4><<<grid, block, 0, stream>>>(
            sino, thetas, positions, out, A, P, N, chunk);
    } else {
        // generic fallback: one batch per z-slice, no chunking
        dim3 grid((nn + 255) / 256, 1);
        for (int b = 0; b < BC; ++b) {
            radon_bwd_kernel<1><<<grid, block, 0, stream>>>(
                sino + (size_t)b * A * P, thetas, positions,
                out + (size_t)b * nn, A, P, N, A);
        }
    }
}